// Round 1
// baseline (35.106 us; speedup 1.0000x reference)
//
#include <hip/hip_runtime.h>

#define NB 2048
#define NC 512
#define ND 256
#define VIG 0.75f

#define BM 64
#define BN 64
#define DK 32
#define NCH (ND / DK)
#define ST 68  // padded k-major stride: 16B-aligned rows, conflict-free b128 reads

__global__ __launch_bounds__(256) void fuzzy_main(const float* __restrict__ x,
                                                  const float* __restrict__ cat,
                                                  float* __restrict__ out) {
  __shared__ float xs[DK][ST];
  __shared__ float cs[DK][ST];
  __shared__ float rs[BM];
  __shared__ float part[BM][4];

  const int t = threadIdx.x;
  const int bm0 = blockIdx.y * BM;
  const int cn0 = blockIdx.x * BN;

  // ---- per-block row sums of x (x is L2-resident; cheap) ----
  {
    const int r = t >> 2, seg = t & 3;
    const float4* xr =
        reinterpret_cast<const float4*>(x + (size_t)(bm0 + r) * ND + seg * 64);
    float s = 0.f;
#pragma unroll
    for (int i = 0; i < 16; ++i) {
      float4 v = xr[i];
      s += v.x + v.y + v.z + v.w;
    }
    part[r][seg] = s;
  }
  __syncthreads();
  if (t < BM) rs[t] = part[t][0] + part[t][1] + part[t][2] + part[t][3];
  // rs becomes visible to all threads at the next __syncthreads below.

  // ---- staging mapping (linear thread order, coalesced float4) ----
  const int sr = t >> 3;       // 0..31
  const int sk = (t & 7) * 4;  // 0,4,...,28
  const float* gx0 = x + (size_t)(bm0 + sr) * ND + sk;
  const float* gx1 = x + (size_t)(bm0 + sr + 32) * ND + sk;
  const float* gc0 = cat + (size_t)(cn0 + sr) * ND + sk;
  const float* gc1 = cat + (size_t)(cn0 + sr + 32) * ND + sk;

  // ---- compute mapping: wave covers 8x8 (tm,tn) -> broadcast LDS reads ----
  const int lane = t & 63, w = t >> 6;
  const int tm = ((w >> 1) << 3) + (lane >> 3);  // 0..15
  const int tn = ((w & 1) << 3) + (lane & 7);    // 0..15
  const int m0 = tm * 4, n0 = tn * 4;

  float acc[4][4] = {};

  float4 pa0, pa1, pb0, pb1;
  pa0 = *reinterpret_cast<const float4*>(gx0);
  pa1 = *reinterpret_cast<const float4*>(gx1);
  pb0 = *reinterpret_cast<const float4*>(gc0);
  pb1 = *reinterpret_cast<const float4*>(gc1);

#define WRLDS()                                                       \
  do {                                                                \
    xs[sk + 0][sr] = pa0.x;  xs[sk + 1][sr] = pa0.y;                  \
    xs[sk + 2][sr] = pa0.z;  xs[sk + 3][sr] = pa0.w;                  \
    xs[sk + 0][sr + 32] = pa1.x;  xs[sk + 1][sr + 32] = pa1.y;        \
    xs[sk + 2][sr + 32] = pa1.z;  xs[sk + 3][sr + 32] = pa1.w;        \
    cs[sk + 0][sr] = pb0.x;  cs[sk + 1][sr] = pb0.y;                  \
    cs[sk + 2][sr] = pb0.z;  cs[sk + 3][sr] = pb0.w;                  \
    cs[sk + 0][sr + 32] = pb1.x;  cs[sk + 1][sr + 32] = pb1.y;        \
    cs[sk + 2][sr + 32] = pb1.z;  cs[sk + 3][sr + 32] = pb1.w;        \
  } while (0)

  WRLDS();
  __syncthreads();

#pragma unroll 1
  for (int ch = 0; ch < NCH; ++ch) {
    if (ch + 1 < NCH) {
      const int kn = (ch + 1) * DK;
      pa0 = *reinterpret_cast<const float4*>(gx0 + kn);
      pa1 = *reinterpret_cast<const float4*>(gx1 + kn);
      pb0 = *reinterpret_cast<const float4*>(gc0 + kn);
      pb1 = *reinterpret_cast<const float4*>(gc1 + kn);
    }
#pragma unroll
    for (int k = 0; k < DK; ++k) {
      float4 a = *reinterpret_cast<const float4*>(&xs[k][m0]);
      float4 b = *reinterpret_cast<const float4*>(&cs[k][n0]);
      float av[4] = {a.x, a.y, a.z, a.w};
      float bv[4] = {b.x, b.y, b.z, b.w};
#pragma unroll
      for (int i = 0; i < 4; ++i)
#pragma unroll
        for (int j = 0; j < 4; ++j) acc[i][j] += fminf(av[i], bv[j]);
    }
    if (ch + 1 < NCH) {
      __syncthreads();
      WRLDS();
      __syncthreads();
    }
  }

  // ---- epilogue: divide (IEEE), threshold, store ----
  float rsm[4];
#pragma unroll
  for (int i = 0; i < 4; ++i) rsm[i] = rs[m0 + i];
#pragma unroll
  for (int i = 0; i < 4; ++i) {
    float4 o;
    float v0 = acc[i][0] / rsm[i];
    float v1 = acc[i][1] / rsm[i];
    float v2 = acc[i][2] / rsm[i];
    float v3 = acc[i][3] / rsm[i];
    o.x = (v0 >= VIG) ? v0 : 0.f;
    o.y = (v1 >= VIG) ? v1 : 0.f;
    o.z = (v2 >= VIG) ? v2 : 0.f;
    o.w = (v3 >= VIG) ? v3 : 0.f;
    *reinterpret_cast<float4*>(out + (size_t)(bm0 + m0 + i) * NC + cn0 + n0) = o;
  }
}

__global__ __launch_bounds__(256) void fuzzy_argmax(const float* __restrict__ scores,
                                                    float* __restrict__ outIdx) {
  const int wv = threadIdx.x >> 6;
  const int lane = threadIdx.x & 63;
  const int row = blockIdx.x * 4 + wv;
  const float* s = scores + (size_t)row * NC;

  float best = -1.0f;
  int bidx = 0;
#pragma unroll
  for (int half = 0; half < 2; ++half) {
    const int j0 = half * 256 + lane * 4;
    float4 v = *reinterpret_cast<const float4*>(s + j0);
    float vv[4] = {v.x, v.y, v.z, v.w};
#pragma unroll
    for (int j = 0; j < 4; ++j) {
      if (vv[j] > best) {  // strict > keeps lowest index (ascending scan)
        best = vv[j];
        bidx = j0 + j;
      }
    }
  }
#pragma unroll
  for (int off = 32; off > 0; off >>= 1) {
    float ob = __shfl_xor(best, off, 64);
    int oi = __shfl_xor(bidx, off, 64);
    if (ob > best || (ob == best && oi < bidx)) {
      best = ob;
      bidx = oi;
    }
  }
  if (lane == 0) outIdx[row] = (float)bidx;
}

extern "C" void kernel_launch(void* const* d_in, const int* in_sizes, int n_in,
                              void* d_out, int out_size, void* d_ws, size_t ws_size,
                              hipStream_t stream) {
  const float* x = (const float*)d_in[0];
  const float* cat = (const float*)d_in[1];
  float* out = (float*)d_out;

  fuzzy_main<<<dim3(NC / BN, NB / BM), 256, 0, stream>>>(x, cat, out);
  fuzzy_argmax<<<NB / 4, 256, 0, stream>>>(out, out + (size_t)NB * NC);
}